// Round 3
// baseline (384.087 us; speedup 1.0000x reference)
//
#include <hip/hip_runtime.h>

#define SEQ 2048
#define DM 1024
#define NH 16
#define HD 64
#define MTOT 4096  // B*SEQ

typedef float f32x4 __attribute__((ext_vector_type(4)));
typedef __bf16 bf16x8 __attribute__((ext_vector_type(8)));
typedef unsigned short u16x8 __attribute__((ext_vector_type(8)));
typedef unsigned short u16x4 __attribute__((ext_vector_type(4)));

__device__ __forceinline__ unsigned short f2bf(float f) {
  union { float f; unsigned u; } v; v.f = f;
  unsigned u = v.u + 0x7FFFu + ((v.u >> 16) & 1u);
  return (unsigned short)(u >> 16);
}

__device__ __forceinline__ f32x4 zero4() { f32x4 z = {0.f, 0.f, 0.f, 0.f}; return z; }

__device__ __forceinline__ f32x4 mfma16(bf16x8 a, bf16x8 b, f32x4 c) {
  return __builtin_amdgcn_mfma_f32_16x16x32_bf16(a, b, c, 0, 0, 0);
}

// ---------------- fp32 -> bf16 convert, 8 elems/thread ----------------
__global__ __launch_bounds__(256) void cvt_bf16(const float* __restrict__ in,
                                                unsigned short* __restrict__ out, int n8) {
  int i = blockIdx.x * 256 + threadIdx.x;
  if (i >= n8) return;
  const f32x4* p = (const f32x4*)(in + (size_t)i * 8);
  f32x4 a = p[0], b = p[1];
  u16x8 o;
  o[0] = f2bf(a[0]); o[1] = f2bf(a[1]); o[2] = f2bf(a[2]); o[3] = f2bf(a[3]);
  o[4] = f2bf(b[0]); o[5] = f2bf(b[1]); o[6] = f2bf(b[2]); o[7] = f2bf(b[3]);
  *(u16x8*)(out + (size_t)i * 8) = o;
}

// ------------- weight fp32 [K][N] -> bf16 transposed [N][K] -------------
__global__ __launch_bounds__(256) void wtrans(const float* __restrict__ wqp, const float* __restrict__ wkp,
                                              const float* __restrict__ wvp, const float* __restrict__ wop,
                                              unsigned short* __restrict__ wt) {
  const float* w = blockIdx.z == 0 ? wqp : blockIdx.z == 1 ? wkp : blockIdx.z == 2 ? wvp : wop;
  unsigned short* o = wt + (size_t)blockIdx.z * DM * DM;
  __shared__ float tile[64][65];
  const int t = threadIdx.x;
  const int k0 = blockIdx.y * 64, n0 = blockIdx.x * 64;
#pragma unroll
  for (int p = 0; p < 4; p++) {
    int r = p * 16 + (t >> 4), c = (t & 15) * 4;
    f32x4 v = *(const f32x4*)&w[(size_t)(k0 + r) * DM + n0 + c];
    tile[r][c] = v[0]; tile[r][c + 1] = v[1]; tile[r][c + 2] = v[2]; tile[r][c + 3] = v[3];
  }
  __syncthreads();
#pragma unroll
  for (int p = 0; p < 4; p++) {
    int r = p * 16 + (t >> 4), c = (t & 15) * 4;
    u16x4 ov;
    ov[0] = f2bf(tile[c][r]); ov[1] = f2bf(tile[c + 1][r]);
    ov[2] = f2bf(tile[c + 2][r]); ov[3] = f2bf(tile[c + 3][r]);
    *(u16x4*)&o[(size_t)(n0 + r) * DM + k0 + c] = ov;
  }
}

// ---------------- shared 128x128xK bf16 GEMM mainloop (A[M][K], Bt[N][K]) ----------------
__device__ __forceinline__ void gemm_body(const unsigned short* __restrict__ A,
                                          const unsigned short* __restrict__ Bt,
                                          unsigned short* a_lds, unsigned short* b_lds,
                                          int m0, int n0, int K, f32x4 acc[4][4]) {
  const int t = threadIdx.x;
  const int lane = t & 63, wid = t >> 6;
  const int wr = wid >> 1, wc = wid & 1;
  const int l15 = lane & 15, lg = lane >> 4;
#pragma unroll
  for (int mi = 0; mi < 4; mi++)
#pragma unroll
    for (int ni = 0; ni < 4; ni++) acc[mi][ni] = zero4();

  const int ar = t >> 2, ac = (t & 3) * 8;
  const unsigned short* gA0 = A + (size_t)(m0 + ar) * K + ac;
  const unsigned short* gA1 = A + (size_t)(m0 + 64 + ar) * K + ac;
  const unsigned short* gB0 = Bt + (size_t)(n0 + ar) * K + ac;
  const unsigned short* gB1 = Bt + (size_t)(n0 + 64 + ar) * K + ac;
  unsigned short* sA0 = a_lds + ar * 32 + ac;
  unsigned short* sA1 = sA0 + 64 * 32;
  unsigned short* sB0 = b_lds + ar * 32 + ac;
  unsigned short* sB1 = sB0 + 64 * 32;
  const unsigned short* rA = a_lds + (wr * 64 + l15) * 32 + lg * 8;
  const unsigned short* rB = b_lds + (wc * 64 + l15) * 32 + lg * 8;

  for (int k0 = 0; k0 < K; k0 += 32) {
    u16x8 va0 = *(const u16x8*)(gA0 + k0);
    u16x8 va1 = *(const u16x8*)(gA1 + k0);
    u16x8 vb0 = *(const u16x8*)(gB0 + k0);
    u16x8 vb1 = *(const u16x8*)(gB1 + k0);
    __syncthreads();  // prior iter's frag reads done before overwrite
    *(u16x8*)sA0 = va0; *(u16x8*)sA1 = va1;
    *(u16x8*)sB0 = vb0; *(u16x8*)sB1 = vb1;
    __syncthreads();
    bf16x8 am[4], bn[4];
#pragma unroll
    for (int mi = 0; mi < 4; mi++) am[mi] = *(const bf16x8*)(rA + mi * 512);
#pragma unroll
    for (int ni = 0; ni < 4; ni++) bn[ni] = *(const bf16x8*)(rB + ni * 512);
#pragma unroll
    for (int mi = 0; mi < 4; mi++)
#pragma unroll
      for (int ni = 0; ni < 4; ni++)
        acc[mi][ni] = mfma16(am[mi], bn[ni], acc[mi][ni]);
  }
}

// ---------------- fused QKV projection: heads layout [B,H,S,64] bf16 ----------------
__global__ __launch_bounds__(256, 2) void qkv_gemm(const unsigned short* __restrict__ xb,
                                                   const unsigned short* __restrict__ wt,
                                                   unsigned short* __restrict__ heads) {
  __shared__ __attribute__((aligned(16))) unsigned short a_lds[128 * 32];
  __shared__ __attribute__((aligned(16))) unsigned short b_lds[128 * 32];
  const int z = blockIdx.z;
  const unsigned short* A = xb + (size_t)z * MTOT * DM;
  const unsigned short* Bt = wt + (size_t)z * DM * DM;
  unsigned short* dst = heads + (size_t)z * MTOT * DM;
  const int m0 = blockIdx.y * 128, n0 = blockIdx.x * 128;
  f32x4 acc[4][4];
  gemm_body(A, Bt, a_lds, b_lds, m0, n0, DM, acc);
  const float scale = (z == 0) ? 0.125f : 1.0f;  // fold 1/sqrt(64) into Q
  const int t = threadIdx.x, lane = t & 63, wid = t >> 6;
  const int wr = wid >> 1, wc = wid & 1, l15 = lane & 15, lg = lane >> 4;
#pragma unroll
  for (int mi = 0; mi < 4; mi++) {
    const int m = m0 + wr * 64 + mi * 16 + lg * 4;
#pragma unroll
    for (int ni = 0; ni < 4; ni++) {
      const int n = n0 + wc * 64 + ni * 16 + l15;
      const int h = n >> 6, d = n & 63;
#pragma unroll
      for (int r = 0; r < 4; r++) {
        const int mm = m + r;
        const int bb = mm >> 11, s = mm & 2047;
        dst[((size_t)(bb * NH + h) * SEQ + s) * HD + d] = f2bf(acc[mi][ni][r] * scale);
      }
    }
  }
}

// ---------------- final projection: ao[4096][1024] @ wo^T -> fp32 out ----------------
__global__ __launch_bounds__(256, 2) void out_gemm(const unsigned short* __restrict__ ao,
                                                   const unsigned short* __restrict__ wot,
                                                   float* __restrict__ out) {
  __shared__ __attribute__((aligned(16))) unsigned short a_lds[128 * 32];
  __shared__ __attribute__((aligned(16))) unsigned short b_lds[128 * 32];
  const int m0 = blockIdx.y * 128, n0 = blockIdx.x * 128;
  f32x4 acc[4][4];
  gemm_body(ao, wot, a_lds, b_lds, m0, n0, DM, acc);
  const int t = threadIdx.x, lane = t & 63, wid = t >> 6;
  const int wr = wid >> 1, wc = wid & 1, l15 = lane & 15, lg = lane >> 4;
#pragma unroll
  for (int mi = 0; mi < 4; mi++) {
    const int m = m0 + wr * 64 + mi * 16 + lg * 4;
#pragma unroll
    for (int ni = 0; ni < 4; ni++) {
      const int n = n0 + wc * 64 + ni * 16 + l15;
#pragma unroll
      for (int r = 0; r < 4; r++)
        out[(size_t)(m + r) * DM + n] = acc[mi][ni][r];
    }
  }
}

// ---------------- flash attention: 1 wave = 16 q rows, 4 waves/block ----------------
__global__ __launch_bounds__(256, 2) void attn(const unsigned short* __restrict__ qh,
                                               const unsigned short* __restrict__ kh,
                                               const unsigned short* __restrict__ vh,
                                               const float* __restrict__ mask,
                                               unsigned short* __restrict__ ao) {
  __shared__ __attribute__((aligned(16))) unsigned short vt[64][40];      // V tile transposed [d][key]
  __shared__ __attribute__((aligned(16))) unsigned short pl[4][16][40];   // per-wave P tile [q][key]
  const int t = threadIdx.x, lane = t & 63, wid = t >> 6;
  const int l15 = lane & 15, lg = lane >> 4;
  const int hh = blockIdx.y, bb = hh >> 4, h = hh & 15;
  const size_t hbase = (size_t)hh * SEQ * HD;
  const unsigned short* Qh = qh + hbase;
  const unsigned short* Kh = kh + hbase;
  const unsigned short* Vh = vh + hbase;
  const float* mrow = mask + bb * SEQ;
  const int qbase = blockIdx.x * 64 + wid * 16;

  // Q held in registers for the whole loop (pre-scaled by 1/8 at projection)
  bf16x8 aq0 = *(const bf16x8*)&Qh[(size_t)(qbase + l15) * HD + lg * 8];
  bf16x8 aq1 = *(const bf16x8*)&Qh[(size_t)(qbase + l15) * HD + 32 + lg * 8];

  f32x4 o[4];
#pragma unroll
  for (int dt = 0; dt < 4; dt++) o[dt] = zero4();
  float mr[4] = {-1e30f, -1e30f, -1e30f, -1e30f};
  float lr[4] = {0.f, 0.f, 0.f, 0.f};

  const int vrow = t >> 3, vc8 = (t & 7) * 8;

  for (int kt = 0; kt < SEQ / 32; kt++) {
    const int kb = kt * 32;
    // prefetch V tile to regs (written to LDS after the barrier)
    u16x8 vv = *(const u16x8*)&Vh[(size_t)(kb + vrow) * HD + vc8];

    // scores: S[16q][32k] as two 16-col C-frags; K read direct from global (L2-resident)
    f32x4 s0 = zero4(), s1 = zero4();
    {
      bf16x8 k00 = *(const bf16x8*)&Kh[(size_t)(kb + l15) * HD + lg * 8];
      bf16x8 k01 = *(const bf16x8*)&Kh[(size_t)(kb + l15) * HD + 32 + lg * 8];
      s0 = mfma16(aq0, k00, s0);
      s0 = mfma16(aq1, k01, s0);
      bf16x8 k10 = *(const bf16x8*)&Kh[(size_t)(kb + 16 + l15) * HD + lg * 8];
      bf16x8 k11 = *(const bf16x8*)&Kh[(size_t)(kb + 16 + l15) * HD + 32 + lg * 8];
      s1 = mfma16(aq0, k10, s1);
      s1 = mfma16(aq1, k11, s1);
    }

    __syncthreads();  // prior iter's vt/pl reads complete
#pragma unroll
    for (int i = 0; i < 8; i++) vt[vc8 + i][vrow] = vv[i];

    const float mv0 = mrow[kb + l15] * -1e9f;
    const float mv1 = mrow[kb + 16 + l15] * -1e9f;

    float corr[4];
#pragma unroll
    for (int r = 0; r < 4; r++) {
      s0[r] += mv0; s1[r] += mv1;
      float v = fmaxf(s0[r], s1[r]);
      v = fmaxf(v, __shfl_xor(v, 1));
      v = fmaxf(v, __shfl_xor(v, 2));
      v = fmaxf(v, __shfl_xor(v, 4));
      v = fmaxf(v, __shfl_xor(v, 8));
      const float mn = fmaxf(mr[r], v);
      corr[r] = exp2f((mr[r] - mn) * 1.44269504f);
      mr[r] = mn;
      const float p0 = exp2f((s0[r] - mn) * 1.44269504f);
      const float p1 = exp2f((s1[r] - mn) * 1.44269504f);
      pl[wid][lg * 4 + r][l15] = f2bf(p0);
      pl[wid][lg * 4 + r][16 + l15] = f2bf(p1);
      float sum = p0 + p1;
      sum += __shfl_xor(sum, 1);
      sum += __shfl_xor(sum, 2);
      sum += __shfl_xor(sum, 4);
      sum += __shfl_xor(sum, 8);
      lr[r] = lr[r] * corr[r] + sum;
    }
#pragma unroll
    for (int dt = 0; dt < 4; dt++) {
      o[dt][0] *= corr[0]; o[dt][1] *= corr[1];
      o[dt][2] *= corr[2]; o[dt][3] *= corr[3];
    }
    __syncthreads();  // vt staged + pl visible
    bf16x8 pa = *(const bf16x8*)&pl[wid][l15][lg * 8];
#pragma unroll
    for (int dt = 0; dt < 4; dt++) {
      bf16x8 bv = *(const bf16x8*)&vt[dt * 16 + l15][lg * 8];
      o[dt] = mfma16(pa, bv, o[dt]);
    }
  }

  float inv[4];
#pragma unroll
  for (int r = 0; r < 4; r++) inv[r] = 1.0f / lr[r];
#pragma unroll
  for (int dt = 0; dt < 4; dt++)
#pragma unroll
    for (int r = 0; r < 4; r++) {
      const int s = qbase + lg * 4 + r;
      ao[(size_t)(bb * SEQ + s) * DM + h * HD + dt * 16 + l15] = f2bf(o[dt][r] * inv[r]);
    }
}

extern "C" void kernel_launch(void* const* d_in, const int* in_sizes, int n_in,
                              void* d_out, int out_size, void* d_ws, size_t ws_size,
                              hipStream_t stream) {
  const float* q = (const float*)d_in[0];
  const float* k = (const float*)d_in[1];
  const float* v = (const float*)d_in[2];
  const float* mask = (const float*)d_in[3];
  const float* wq = (const float*)d_in[4];
  const float* wk = (const float*)d_in[5];
  const float* wv = (const float*)d_in[6];
  const float* wo = (const float*)d_in[7];
  float* out = (float*)d_out;

  const size_t SZX = (size_t)MTOT * DM;  // 4 Mi elems
  unsigned short* ws = (unsigned short*)d_ws;
  unsigned short* xb = ws;                         // 3*SZX bf16 (q,k,v converted)
  unsigned short* wt = xb + 3 * SZX;               // 4*DM*DM bf16 (wq,wk,wv,wo transposed)
  unsigned short* heads = wt + 4 * (size_t)DM * DM; // 3*SZX bf16 (qh,kh,vh)
  unsigned short* ao = xb;                         // reuse xb: attn output [B,S,DM]
  const size_t need = (3 * SZX + 4 * (size_t)DM * DM + 3 * SZX) * sizeof(unsigned short);
  if (ws_size < need) return;  // fail loudly (output stays poisoned)

  cvt_bf16<<<dim3(2048), dim3(256), 0, stream>>>(q, xb, (int)(SZX / 8));
  cvt_bf16<<<dim3(2048), dim3(256), 0, stream>>>(k, xb + SZX, (int)(SZX / 8));
  cvt_bf16<<<dim3(2048), dim3(256), 0, stream>>>(v, xb + 2 * SZX, (int)(SZX / 8));
  wtrans<<<dim3(16, 16, 4), dim3(256), 0, stream>>>(wq, wk, wv, wo, wt);
  qkv_gemm<<<dim3(8, 32, 3), dim3(256), 0, stream>>>(xb, wt, heads);
  attn<<<dim3(32, 32), dim3(256), 0, stream>>>(heads, heads + SZX, heads + 2 * SZX, mask, ao);
  out_gemm<<<dim3(8, 32), dim3(256), 0, stream>>>(ao, wt + 3 * (size_t)DM * DM, out);
}

// Round 13
// 348.511 us; speedup vs baseline: 1.1021x; 1.1021x over previous
//
#include <hip/hip_runtime.h>

#define SEQ 2048
#define DM 1024
#define NH 16
#define HD 64
#define MTOT 4096  // B*S

#ifndef __has_builtin
#define __has_builtin(x) 0
#endif
#if __has_builtin(__builtin_amdgcn_global_load_lds)
#define HAS_GLL 1
#define GLL16(gsrc, ldst)                                    \
  __builtin_amdgcn_global_load_lds(                          \
      (const __attribute__((address_space(1))) void*)(gsrc), \
      (__attribute__((address_space(3))) void*)(ldst), 16, 0, 0)
#endif

typedef float f32x4 __attribute__((ext_vector_type(4)));
typedef __bf16 bf16x8 __attribute__((ext_vector_type(8)));
typedef unsigned short u16x8 __attribute__((ext_vector_type(8)));
typedef unsigned short u16x4 __attribute__((ext_vector_type(4)));

__device__ __forceinline__ unsigned short f2bf(float f) {
  union { __bf16 h; unsigned short u; } v;
  v.h = (__bf16)f;  // RTNE hw convert; compiler packs pairs as v_cvt_pk_bf16_f32
  return v.u;
}

__device__ __forceinline__ f32x4 zero4() { f32x4 z = {0.f, 0.f, 0.f, 0.f}; return z; }

__device__ __forceinline__ f32x4 mfma16(bf16x8 a, bf16x8 b, f32x4 c) {
  return __builtin_amdgcn_mfma_f32_16x16x32_bf16(a, b, c, 0, 0, 0);
}

// ---------------- fp32 -> bf16 convert, 8 elems/thread ----------------
__global__ __launch_bounds__(256) void cvt_bf16(const float* __restrict__ in,
                                                unsigned short* __restrict__ out, int n8) {
  int i = blockIdx.x * 256 + threadIdx.x;
  if (i >= n8) return;
  const f32x4* p = (const f32x4*)(in + (size_t)i * 8);
  f32x4 a = p[0], b = p[1];
  u16x8 o;
  o[0] = f2bf(a[0]); o[1] = f2bf(a[1]); o[2] = f2bf(a[2]); o[3] = f2bf(a[3]);
  o[4] = f2bf(b[0]); o[5] = f2bf(b[1]); o[6] = f2bf(b[2]); o[7] = f2bf(b[3]);
  *(u16x8*)(out + (size_t)i * 8) = o;
}

// ------------- weight fp32 [K][N] -> bf16 transposed [N][K] -------------
__global__ __launch_bounds__(256) void wtrans(const float* __restrict__ wqp, const float* __restrict__ wkp,
                                              const float* __restrict__ wvp, const float* __restrict__ wop,
                                              unsigned short* __restrict__ wt) {
  const float* w = blockIdx.z == 0 ? wqp : blockIdx.z == 1 ? wkp : blockIdx.z == 2 ? wvp : wop;
  unsigned short* o = wt + (size_t)blockIdx.z * DM * DM;
  __shared__ float tile[64][65];
  const int t = threadIdx.x;
  const int k0 = blockIdx.y * 64, n0 = blockIdx.x * 64;
#pragma unroll
  for (int p = 0; p < 4; p++) {
    int r = p * 16 + (t >> 4), c = (t & 15) * 4;
    f32x4 v = *(const f32x4*)&w[(size_t)(k0 + r) * DM + n0 + c];
    tile[r][c] = v[0]; tile[r][c + 1] = v[1]; tile[r][c + 2] = v[2]; tile[r][c + 3] = v[3];
  }
  __syncthreads();
#pragma unroll
  for (int p = 0; p < 4; p++) {
    int r = p * 16 + (t >> 4), c = (t & 15) * 4;
    u16x4 ov;
    ov[0] = f2bf(tile[c][r]); ov[1] = f2bf(tile[c + 1][r]);
    ov[2] = f2bf(tile[c + 2][r]); ov[3] = f2bf(tile[c + 3][r]);
    *(u16x4*)&o[(size_t)(n0 + r) * DM + k0 + c] = ov;
  }
}

// ------- shared 128x128xK bf16 GEMM mainloop (A[M][K], Bt[N][K]), GLL staging -------
__device__ __forceinline__ void gemm_body(const unsigned short* __restrict__ A,
                                          const unsigned short* __restrict__ Bt,
                                          unsigned short* a_lds, unsigned short* b_lds,
                                          int m0, int n0, int K, f32x4 acc[4][4]) {
  const int t = threadIdx.x;
  const int lane = t & 63, wid = t >> 6;
  const int wr = wid >> 1, wc = wid & 1;
  const int l15 = lane & 15, lg = lane >> 4;
#pragma unroll
  for (int mi = 0; mi < 4; mi++)
#pragma unroll
    for (int ni = 0; ni < 4; ni++) acc[mi][ni] = zero4();

  const int ar = t >> 2, ac = (t & 3) * 8;  // note: ar*32+ac == t*8 (linear 16B/thread)
  const unsigned short* gA0 = A + (size_t)(m0 + ar) * K + ac;
  const unsigned short* gA1 = A + (size_t)(m0 + 64 + ar) * K + ac;
  const unsigned short* gB0 = Bt + (size_t)(n0 + ar) * K + ac;
  const unsigned short* gB1 = Bt + (size_t)(n0 + 64 + ar) * K + ac;
  unsigned short* sA0 = a_lds + t * 8;
  unsigned short* sA1 = a_lds + 64 * 32 + t * 8;
  unsigned short* sB0 = b_lds + t * 8;
  unsigned short* sB1 = b_lds + 64 * 32 + t * 8;
  const unsigned short* rA = a_lds + (wr * 64 + l15) * 32 + lg * 8;
  const unsigned short* rB = b_lds + (wc * 64 + l15) * 32 + lg * 8;

  for (int k0 = 0; k0 < K; k0 += 32) {
#ifdef HAS_GLL
    __syncthreads();  // prior iter's frag reads done before overwrite
    GLL16(gA0 + k0, sA0);
    GLL16(gA1 + k0, sA1);
    GLL16(gB0 + k0, sB0);
    GLL16(gB1 + k0, sB1);
    __syncthreads();  // vmcnt(0) drain + visibility
#else
    u16x8 va0 = *(const u16x8*)(gA0 + k0);
    u16x8 va1 = *(const u16x8*)(gA1 + k0);
    u16x8 vb0 = *(const u16x8*)(gB0 + k0);
    u16x8 vb1 = *(const u16x8*)(gB1 + k0);
    __syncthreads();
    *(u16x8*)sA0 = va0; *(u16x8*)sA1 = va1;
    *(u16x8*)sB0 = vb0; *(u16x8*)sB1 = vb1;
    __syncthreads();
#endif
    bf16x8 am[4], bn[4];
#pragma unroll
    for (int mi = 0; mi < 4; mi++) am[mi] = *(const bf16x8*)(rA + mi * 512);
#pragma unroll
    for (int ni = 0; ni < 4; ni++) bn[ni] = *(const bf16x8*)(rB + ni * 512);
#pragma unroll
    for (int mi = 0; mi < 4; mi++)
#pragma unroll
      for (int ni = 0; ni < 4; ni++)
        acc[mi][ni] = mfma16(am[mi], bn[ni], acc[mi][ni]);
  }
}

// ---- fused QKV projection: Q/K -> [B,H,S,64]; V -> transposed [B,H,64,S] ----
__global__ __launch_bounds__(256, 2) void qkv_gemm(const unsigned short* __restrict__ xb,
                                                   const unsigned short* __restrict__ wt,
                                                   unsigned short* __restrict__ heads) {
  __shared__ __attribute__((aligned(16))) unsigned short a_lds[128 * 32];
  __shared__ __attribute__((aligned(16))) unsigned short b_lds[128 * 32];
  const int z = blockIdx.z;
  const unsigned short* A = xb + (size_t)z * MTOT * DM;
  const unsigned short* Bt = wt + (size_t)z * DM * DM;
  unsigned short* dst = heads + (size_t)z * MTOT * DM;
  const int m0 = blockIdx.y * 128, n0 = blockIdx.x * 128;
  f32x4 acc[4][4];
  gemm_body(A, Bt, a_lds, b_lds, m0, n0, DM, acc);
  const int t = threadIdx.x, lane = t & 63, wid = t >> 6;
  const int wr = wid >> 1, wc = wid & 1, l15 = lane & 15, lg = lane >> 4;
  if (z == 2) {
    // V^T layout [B,H,64,S]: 4 consecutive r -> 4 consecutive s => u16x4 stores
#pragma unroll
    for (int mi = 0; mi < 4; mi++) {
      const int m = m0 + wr * 64 + mi * 16 + lg * 4;
      const int bb = m >> 11, s = m & 2047;
#pragma unroll
      for (int ni = 0; ni < 4; ni++) {
        const int n = n0 + wc * 64 + ni * 16 + l15;
        const int h = n >> 6, d = n & 63;
        u16x4 ov;
#pragma unroll
        for (int r = 0; r < 4; r++) ov[r] = f2bf(acc[mi][ni][r]);
        *(u16x4*)&dst[((size_t)(bb * NH + h) * HD + d) * SEQ + s] = ov;
      }
    }
  } else {
    const float scale = (z == 0) ? 0.125f : 1.0f;  // fold 1/sqrt(64) into Q
#pragma unroll
    for (int mi = 0; mi < 4; mi++) {
      const int m = m0 + wr * 64 + mi * 16 + lg * 4;
#pragma unroll
      for (int ni = 0; ni < 4; ni++) {
        const int n = n0 + wc * 64 + ni * 16 + l15;
        const int h = n >> 6, d = n & 63;
#pragma unroll
        for (int r = 0; r < 4; r++) {
          const int mm = m + r;
          const int bb = mm >> 11, s = mm & 2047;
          dst[((size_t)(bb * NH + h) * SEQ + s) * HD + d] = f2bf(acc[mi][ni][r] * scale);
        }
      }
    }
  }
}

// ---------------- final projection: ao[4096][1024] @ wo^T -> fp32 out ----------------
__global__ __launch_bounds__(256, 2) void out_gemm(const unsigned short* __restrict__ ao,
                                                   const unsigned short* __restrict__ wot,
                                                   float* __restrict__ out) {
  __shared__ __attribute__((aligned(16))) unsigned short a_lds[128 * 32];
  __shared__ __attribute__((aligned(16))) unsigned short b_lds[128 * 32];
  const int m0 = blockIdx.y * 128, n0 = blockIdx.x * 128;
  f32x4 acc[4][4];
  gemm_body(ao, wot, a_lds, b_lds, m0, n0, DM, acc);
  const int t = threadIdx.x, lane = t & 63, wid = t >> 6;
  const int wr = wid >> 1, wc = wid & 1, l15 = lane & 15, lg = lane >> 4;
#pragma unroll
  for (int mi = 0; mi < 4; mi++) {
    const int m = m0 + wr * 64 + mi * 16 + lg * 4;
#pragma unroll
    for (int ni = 0; ni < 4; ni++) {
      const int n = n0 + wc * 64 + ni * 16 + l15;
#pragma unroll
      for (int r = 0; r < 4; r++)
        out[(size_t)(m + r) * DM + n] = acc[mi][ni][r];
    }
  }
}

// -------- flash attention v2: LDS-staged K (swizzled) + V^T (linear, dbuf, prefetch) --------
__global__ __launch_bounds__(256, 2) void attn(const unsigned short* __restrict__ qh,
                                               const unsigned short* __restrict__ kh,
                                               const unsigned short* __restrict__ vht,
                                               const float* __restrict__ mask,
                                               unsigned short* __restrict__ ao) {
  __shared__ __attribute__((aligned(16))) unsigned short klds[32 * 64];     // [key][d], 16B-chunk XOR swizzle
  __shared__ __attribute__((aligned(16))) unsigned short vlds[2][64 * 32];  // [d][key], linear (rows=64B)
  __shared__ __attribute__((aligned(16))) __bf16 pl[4][16][40];             // per-wave P, group-swizzled cols
  const int t = threadIdx.x, lane = t & 63, wid = t >> 6;
  const int l15 = lane & 15, lg = lane >> 4;
  const int hh = blockIdx.y, bb = hh >> 4, h = hh & 15;
  const size_t hbase = (size_t)hh * SEQ * HD;
  const unsigned short* Qh = qh + hbase;
  const unsigned short* Kh = kh + hbase;
  const unsigned short* VhT = vht + hbase;  // [64][2048]
  const float* mrow = mask + bb * SEQ;
  const int qbase = blockIdx.x * 64 + wid * 16;

  // Q in registers (pre-scaled by 1/8 at projection)
  bf16x8 aq0 = *(const bf16x8*)&Qh[(size_t)(qbase + l15) * HD + lg * 8];
  bf16x8 aq1 = *(const bf16x8*)&Qh[(size_t)(qbase + l15) * HD + 32 + lg * 8];

  f32x4 o[4];
#pragma unroll
  for (int dt = 0; dt < 4; dt++) o[dt] = zero4();
  float mr[4] = {-1e30f, -1e30f, -1e30f, -1e30f};
  float lr[4] = {0.f, 0.f, 0.f, 0.f};

  // staging addresses (256 threads cover one 32x64 K tile and one 64x32 V^T tile)
  const int krow = t >> 3, kc = t & 7;
  const unsigned short* gK = &Kh[(size_t)krow * HD + kc * 8];
  unsigned short* sK = &klds[krow * 64 + ((kc ^ (krow & 7)) * 8)];
  const unsigned short* gV = &VhT[(size_t)(t >> 2) * SEQ + (t & 3) * 8];

  // K frag pointers (swizzled chunks)
  const unsigned short* rK0a = &klds[l15 * 64 + ((lg ^ (l15 & 7)) * 8)];
  const unsigned short* rK0b = &klds[l15 * 64 + (((4 + lg) ^ (l15 & 7)) * 8)];
  const unsigned short* rK1a = &klds[(16 + l15) * 64 + ((lg ^ (l15 & 7)) * 8)];
  const unsigned short* rK1b = &klds[(16 + l15) * 64 + (((4 + lg) ^ (l15 & 7)) * 8)];
  // pl swizzled columns: store col = (g ^ (q>>2))*8 + (key&7); read base (g ^ (q>>2))*8
  const int pc0 = (((l15 >> 3) ^ lg) * 8) + (l15 & 7);
  const int pc1 = ((((l15 >> 3) + 2) ^ lg) * 8) + (l15 & 7);
  const int prc = (lg ^ ((l15 >> 2) & 3)) * 8;

  // tile-0 prefetch
  u16x8 kreg = *(const u16x8*)gK;
#ifdef HAS_GLL
  GLL16(gV, &vlds[0][t * 8]);
#else
  { u16x8 vr = *(const u16x8*)gV; *(u16x8*)&vlds[0][t * 8] = vr; }
#endif

  for (int kt = 0; kt < SEQ / 32; kt++) {
    const int cur = kt & 1;
    const int kb = kt * 32;
    __syncthreads();  // (a) prior tile's klds/vlds reads done
    *(u16x8*)sK = kreg;
    __syncthreads();  // (b) K visible; V global_load_lds drained (vmcnt 0 at barrier)
    if (kt + 1 < SEQ / 32) {  // prefetch next tile (hidden under this tile's compute)
      const int kb1 = kb + 32;
      kreg = *(const u16x8*)(gK + (size_t)kb1 * HD);
#ifdef HAS_GLL
      GLL16(gV + kb1, &vlds[cur ^ 1][t * 8]);
#else
      { u16x8 vr = *(const u16x8*)(gV + kb1); *(u16x8*)&vlds[cur ^ 1][t * 8] = vr; }
#endif
    }

    // QK^T: S[16q][32k] as two C-frags
    f32x4 s0 = zero4(), s1 = zero4();
    s0 = mfma16(aq0, *(const bf16x8*)rK0a, s0);
    s0 = mfma16(aq1, *(const bf16x8*)rK0b, s0);
    s1 = mfma16(aq0, *(const bf16x8*)rK1a, s1);
    s1 = mfma16(aq1, *(const bf16x8*)rK1b, s1);

    // V B-frags (independent of softmax -> issue early)
    const unsigned short* vb = &vlds[cur][0];
    bf16x8 bv0 = *(const bf16x8*)&vb[(0 * 16 + l15) * 32 + lg * 8];
    bf16x8 bv1 = *(const bf16x8*)&vb[(1 * 16 + l15) * 32 + lg * 8];
    bf16x8 bv2 = *(const bf16x8*)&vb[(2 * 16 + l15) * 32 + lg * 8];
    bf16x8 bv3 = *(const bf16x8*)&vb[(3 * 16 + l15) * 32 + lg * 8];

    const float mv0 = mrow[kb + l15] * -1e9f;
    const float mv1 = mrow[kb + 16 + l15] * -1e9f;

    float corr[4];
#pragma unroll
    for (int r = 0; r < 4; r++) {
      s0[r] += mv0; s1[r] += mv1;
      float v = fmaxf(s0[r], s1[r]);
      v = fmaxf(v, __shfl_xor(v, 1));
      v = fmaxf(v, __shfl_xor(v, 2));
      v = fmaxf(v, __shfl_xor(v, 4));
      v = fmaxf(v, __shfl_xor(v, 8));
      const float mn = fmaxf(mr[r], v);
      corr[r] = exp2f((mr[r] - mn) * 1.44269504f);
      mr[r] = mn;
      const float p0 = exp2f((s0[r] - mn) * 1.44269504f);
      const float p1 = exp2f((s1[r] - mn) * 1.44269504f);
      pl[wid][lg * 4 + r][pc0] = (__bf16)p0;
      pl[wid][lg * 4 + r][pc1] = (__bf16)p1;
      float sum = p0 + p1;
      sum += __shfl_xor(sum, 1);
      sum += __shfl_xor(sum, 2);
      sum += __shfl_xor(sum, 4);
      sum += __shfl_xor(sum, 8);
      lr[r] = lr[r] * corr[r] + sum;
    }
#pragma unroll
    for (int dt = 0; dt < 4; dt++) {
      o[dt][0] *= corr[0]; o[dt][1] *= corr[1];
      o[dt][2] *= corr[2]; o[dt][3] *= corr[3];
    }
    bf16x8 pa = *(const bf16x8*)&pl[wid][l15][prc];
    o[0] = mfma16(pa, bv0, o[0]);
    o[1] = mfma16(pa, bv1, o[1]);
    o[2] = mfma16(pa, bv2, o[2]);
    o[3] = mfma16(pa, bv3, o[3]);
  }

  float inv[4];
#pragma unroll
  for (int r = 0; r < 4; r++) inv[r] = 1.0f / lr[r];
#pragma unroll
  for (int dt = 0; dt < 4; dt++)
#pragma unroll
    for (int r = 0; r < 4; r++) {
      const int s = qbase + lg * 4 + r;
      ao[(size_t)(bb * SEQ + s) * DM + h * HD + dt * 16 + l15] = f2bf(o[dt][r] * inv[r]);
    }
}

extern "C" void kernel_launch(void* const* d_in, const int* in_sizes, int n_in,
                              void* d_out, int out_size, void* d_ws, size_t ws_size,
                              hipStream_t stream) {
  const float* q = (const float*)d_in[0];
  const float* k = (const float*)d_in[1];
  const float* v = (const float*)d_in[2];
  const float* mask = (const float*)d_in[3];
  const float* wq = (const float*)d_in[4];
  const float* wk = (const float*)d_in[5];
  const float* wv = (const float*)d_in[6];
  const float* wo = (const float*)d_in[7];
  float* out = (float*)d_out;

  const size_t SZX = (size_t)MTOT * DM;  // 4 Mi elems
  unsigned short* ws = (unsigned short*)d_ws;
  unsigned short* xb = ws;                          // 3*SZX bf16 (q,k,v converted)
  unsigned short* wt = xb + 3 * SZX;                // 4*DM*DM bf16 (weights transposed)
  unsigned short* heads = wt + 4 * (size_t)DM * DM; // 3*SZX bf16 (qh,kh,vhT)
  unsigned short* ao = xb;                          // reuse xb: attn output [B,S,DM]
  const size_t need = (3 * SZX + 4 * (size_t)DM * DM + 3 * SZX) * sizeof(unsigned short);
  if (ws_size < need) return;  // fail loudly (output stays poisoned)

  cvt_bf16<<<dim3(2048), dim3(256), 0, stream>>>(q, xb, (int)(SZX / 8));
  cvt_bf16<<<dim3(2048), dim3(256), 0, stream>>>(k, xb + SZX, (int)(SZX / 8));
  cvt_bf16<<<dim3(2048), dim3(256), 0, stream>>>(v, xb + 2 * SZX, (int)(SZX / 8));
  wtrans<<<dim3(16, 16, 4), dim3(256), 0, stream>>>(wq, wk, wv, wo, wt);
  qkv_gemm<<<dim3(8, 32, 3), dim3(256), 0, stream>>>(xb, wt, heads);
  attn<<<dim3(32, 32), dim3(256), 0, stream>>>(heads, heads + SZX, heads + 2 * SZX, mask, ao);
  out_gemm<<<dim3(8, 32), dim3(256), 0, stream>>>(ao, wt + 3 * (size_t)DM * DM, out);
}